// Round 1
// baseline (3391.259 us; speedup 1.0000x reference)
//
#include <hip/hip_runtime.h>
#include <hip/hip_bf16.h>

typedef __bf16 bf16_t;
typedef __bf16 bf16x8 __attribute__((ext_vector_type(8)));
typedef __bf16 bf16x4 __attribute__((ext_vector_type(4)));
typedef float f32x4 __attribute__((ext_vector_type(4)));

#define DEVI static __device__ __forceinline__

DEVI f32x4 mfma16(bf16x8 a, bf16x8 b, f32x4 c) {
  return __builtin_amdgcn_mfma_f32_16x16x32_bf16(a, b, c, 0, 0, 0);
}

DEVI float sigf(float x) { return 1.f / (1.f + __expf(-x)); }
DEVI float tanh_fast(float x) { return 2.f / (1.f + __expf(-2.f * x)) - 1.f; }

// ---------------------------------------------------------------------------
// Pre-swizzle weight matrix W [K,N] (f32 row-major) into B-fragment-major bf16:
// Wsw[kc][nt][lane][j] = W[kc*32 + (lane>>4)*8 + j][nt*16 + (lane&15)]
// so a wave's B-fragment for MFMA tile (kc,nt) is 64 lanes x 16B contiguous.
// ---------------------------------------------------------------------------
__global__ __launch_bounds__(256) void k_prep(const float* __restrict__ src,
                                              bf16_t* __restrict__ dst,
                                              int K, int N) {
  int gid = blockIdx.x * 256 + threadIdx.x;
  int total = (K / 32) * (N / 16) * 64;
  if (gid >= total) return;
  int l = gid & 63;
  int fi = gid >> 6;
  int NT = N >> 4;
  int nt = fi % NT;
  int kc = fi / NT;
  int row0 = kc * 32 + (l >> 4) * 8;
  int col = nt * 16 + (l & 15);
  bf16x8 v;
#pragma unroll
  for (int j = 0; j < 8; ++j) v[j] = (bf16_t)src[(size_t)(row0 + j) * N + col];
  *(bf16x8*)(dst + (size_t)gid * 8) = v;
}

// ---------------------------------------------------------------------------
// Input projection: xg[t] = x[:, t_eff, :] @ Wx + b  for one direction.
// x: [128][T][KDIM] f32.  Grid: T*8 WGs; WG = (t, 256-col chunk), 4 waves 2x2.
// Output xg in C-fragment-major layout:
//   xg[((t*8 + mt)*128 + nt)*64 + lane][r]  (bf16, r=0..3)
// where fragment (mt,nt) covers rows mt*16.. and cols nt*16.., and the C
// mapping is row=(lane>>4)*4+r, col=lane&15.
// ---------------------------------------------------------------------------
template <int KDIM>
__global__ __launch_bounds__(256) void k_proj(const float* __restrict__ x, int T,
                                              int dir,
                                              const bf16_t* __restrict__ Wsw,
                                              const float* __restrict__ bias,
                                              bf16_t* __restrict__ xg) {
  int chunk = blockIdx.x & 7;
  int t = blockIdx.x >> 3;
  int tt = dir ? (T - 1 - t) : t;
  int tid = threadIdx.x;
  int l = tid & 63, w = tid >> 6;
  int wr = w >> 1, wc = w & 1;
  int rl = l & 15, kl = (l >> 4) * 8;
  f32x4 acc[4][8];
#pragma unroll
  for (int mt = 0; mt < 4; ++mt)
#pragma unroll
    for (int nt = 0; nt < 8; ++nt) acc[mt][nt] = f32x4{0.f, 0.f, 0.f, 0.f};

  for (int kc = 0; kc < KDIM / 32; ++kc) {
    bf16x8 a[4];
#pragma unroll
    for (int mt = 0; mt < 4; ++mt) {
      int chain = wr * 64 + mt * 16 + rl;
      const float* p = x + ((size_t)chain * T + tt) * KDIM + kc * 32 + kl;
      float4 u = *(const float4*)p;
      float4 v = *(const float4*)(p + 4);
      bf16x8 av;
      av[0] = (bf16_t)u.x; av[1] = (bf16_t)u.y; av[2] = (bf16_t)u.z; av[3] = (bf16_t)u.w;
      av[4] = (bf16_t)v.x; av[5] = (bf16_t)v.y; av[6] = (bf16_t)v.z; av[7] = (bf16_t)v.w;
      a[mt] = av;
    }
#pragma unroll
    for (int nt = 0; nt < 8; ++nt) {
      int nt_g = chunk * 16 + wc * 8 + nt;
      bf16x8 b = *(const bf16x8*)(Wsw + ((size_t)(kc * 128 + nt_g) * 64 + l) * 8);
#pragma unroll
      for (int mt = 0; mt < 4; ++mt) acc[mt][nt] = mfma16(a[mt], b, acc[mt][nt]);
    }
  }

#pragma unroll
  for (int mt = 0; mt < 4; ++mt) {
    int mt_g = wr * 4 + mt;
#pragma unroll
    for (int nt = 0; nt < 8; ++nt) {
      int nt_g = chunk * 16 + wc * 8 + nt;
      float bv = bias[nt_g * 16 + rl];
      bf16x4 ov;
#pragma unroll
      for (int r = 0; r < 4; ++r) ov[r] = (bf16_t)(acc[mt][nt][r] + bv);
      *(bf16x4*)(xg + (((size_t)(t * 8 + mt_g) * 128 + nt_g) * 64 + l) * 4) = ov;
    }
  }
}

// ---------------------------------------------------------------------------
// One LSTM time step for all chains. Grid: 256 WGs while text live (s<64),
// else 128. WG = (vid/txt, dir, 64-chain half mb, 16-col j-tile jt).
// gates = xg[s] + h_prev @ Wh ; per-wave: 16 rows x (4 gates x 16 cols).
// h double-buffered by step parity; c owned exclusively per WG slice.
// ---------------------------------------------------------------------------
__global__ __launch_bounds__(256) void k_step(
    const bf16_t* __restrict__ xg_vid, const bf16_t* __restrict__ xg_txt,
    const bf16_t* __restrict__ Wh_vid, const bf16_t* __restrict__ Wh_txt,
    bf16_t* __restrict__ h_vid, bf16_t* __restrict__ h_txt,
    float* __restrict__ c_vid, float* __restrict__ c_txt,
    bf16_t* __restrict__ feats, int s) {
  int bid = blockIdx.x;
  bool istxt = bid >= 128;
  int b2 = bid & 127;
  int dir = (b2 >> 6) & 1, mb = (b2 >> 5) & 1, jt = b2 & 31;
  const bf16_t* xg;
  const bf16_t* Wh;
  bf16_t* hb;
  float* cb;
  int lastT, colbase;
  if (istxt) {
    xg = xg_txt + ((size_t)dir * 64 + s) * (128 * 2048);
    Wh = Wh_txt + (size_t)dir * (512 * 2048);
    hb = h_txt;
    cb = c_txt + (size_t)dir * (128 * 512);
    lastT = 63;
    colbase = 1024 + dir * 512;
  } else {
    xg = xg_vid + ((size_t)dir * 256 + s) * (128 * 2048);
    Wh = Wh_vid + (size_t)dir * (512 * 2048);
    hb = h_vid;
    cb = c_vid + (size_t)dir * (128 * 512);
    lastT = 255;
    colbase = dir * 512;
  }
  const bf16_t* hprev = hb + ((size_t)(s & 1) * 2 + dir) * (128 * 512);
  bf16_t* hnext = hb + ((size_t)((s + 1) & 1) * 2 + dir) * (128 * 512);

  int tid = threadIdx.x;
  int l = tid & 63, w = tid >> 6;
  int rl = l & 15, kl = (l >> 4) * 8;
  int mt_g = mb * 4 + w;   // global 16-row tile index (0..7)
  int c0 = mt_g * 16;      // chain base for this wave

  f32x4 acc[4];
#pragma unroll
  for (int g = 0; g < 4; ++g) {
    int nt_g = g * 32 + jt;
    bf16x4 xv = *(const bf16x4*)(xg + (((size_t)mt_g * 128 + nt_g) * 64 + l) * 4);
    acc[g] = f32x4{(float)xv[0], (float)xv[1], (float)xv[2], (float)xv[3]};
  }

  const bf16_t* hrow = hprev + (size_t)(c0 + rl) * 512 + kl;
#pragma unroll 4
  for (int kc = 0; kc < 16; ++kc) {
    bf16x8 a = *(const bf16x8*)(hrow + kc * 32);
#pragma unroll
    for (int g = 0; g < 4; ++g) {
      int nt_g = g * 32 + jt;
      bf16x8 b = *(const bf16x8*)(Wh + ((size_t)(kc * 128 + nt_g) * 64 + l) * 8);
      acc[g] = mfma16(a, b, acc[g]);
    }
  }

  int j = jt * 16 + rl;
#pragma unroll
  for (int r = 0; r < 4; ++r) {
    int chain = c0 + (l >> 4) * 4 + r;
    float iv = acc[0][r], fv = acc[1][r], gv = acc[2][r], ov = acc[3][r];
    float* cp = cb + (size_t)chain * 512 + j;
    float cold = *cp;
    float cn = sigf(fv) * cold + sigf(iv) * tanh_fast(gv);
    *cp = cn;
    float hn = sigf(ov) * tanh_fast(cn);
    hnext[(size_t)chain * 512 + j] = (bf16_t)hn;
    if (s == lastT) feats[(size_t)chain * 2048 + colbase + j] = (bf16_t)hn;
  }
}

// ---------------------------------------------------------------------------
// h1[mlp] = relu(feats @ W1[mlp] + b1[mlp]) : [128,2048]x[2048,512]
// Grid: 16 WGs = 2 mlps x 8 column chunks of 64.
// ---------------------------------------------------------------------------
__global__ __launch_bounds__(256) void k_mlp(const bf16_t* __restrict__ feats,
                                             const bf16_t* __restrict__ W1sw,
                                             const float* __restrict__ sqb1,
                                             const float* __restrict__ rqb1,
                                             float* __restrict__ h1) {
  int mlp = blockIdx.x >> 3, chunk = blockIdx.x & 7;
  const bf16_t* Wsw = W1sw + (size_t)mlp * (2048 * 512);
  const float* b1 = mlp ? rqb1 : sqb1;
  int tid = threadIdx.x;
  int l = tid & 63, w = tid >> 6;
  int rl = l & 15, kl = (l >> 4) * 8;
  f32x4 acc[2][4];
#pragma unroll
  for (int mt = 0; mt < 2; ++mt)
#pragma unroll
    for (int nt = 0; nt < 4; ++nt) acc[mt][nt] = f32x4{0.f, 0.f, 0.f, 0.f};

  for (int kc = 0; kc < 64; ++kc) {
    bf16x8 a[2];
#pragma unroll
    for (int mt = 0; mt < 2; ++mt) {
      int row = w * 32 + mt * 16 + rl;
      a[mt] = *(const bf16x8*)(feats + (size_t)row * 2048 + kc * 32 + kl);
    }
#pragma unroll
    for (int nt = 0; nt < 4; ++nt) {
      int nt_g = chunk * 4 + nt;
      bf16x8 b = *(const bf16x8*)(Wsw + ((size_t)(kc * 32 + nt_g) * 64 + l) * 8);
#pragma unroll
      for (int mt = 0; mt < 2; ++mt) acc[mt][nt] = mfma16(a[mt], b, acc[mt][nt]);
    }
  }

#pragma unroll
  for (int mt = 0; mt < 2; ++mt)
#pragma unroll
    for (int nt = 0; nt < 4; ++nt) {
      int col = (chunk * 4 + nt) * 16 + rl;
      float bv = b1[col];
#pragma unroll
      for (int r = 0; r < 4; ++r) {
        int row = w * 32 + mt * 16 + (l >> 4) * 4 + r;
        float v = acc[mt][nt][r] + bv;
        h1[(size_t)mlp * (128 * 512) + (size_t)row * 512 + col] = v > 0.f ? v : 0.f;
      }
    }
}

// ---------------------------------------------------------------------------
// scores + label-select + mean over S + sigmoid -> out[16]
// ---------------------------------------------------------------------------
__global__ __launch_bounds__(256) void k_final(const float* __restrict__ h1,
                                               const float* __restrict__ sqW2,
                                               const float* __restrict__ sqb2,
                                               const float* __restrict__ rqW2,
                                               const float* __restrict__ rqb2,
                                               const int* __restrict__ labels,
                                               float* __restrict__ out) {
  __shared__ float sc[128][2];
  int tid = threadIdx.x;
  int row = tid >> 1, m = tid & 1;
  const float* hp = h1 + ((size_t)m * 128 + row) * 512;
  const float* w2 = m ? rqW2 : sqW2;
  float s = m ? *rqb2 : *sqb2;
  for (int k = 0; k < 512; ++k) s += hp[k] * w2[k];
  sc[row][m] = s;
  __syncthreads();
  if (tid < 16) {
    float acc = 0.f;
    for (int i = 0; i < 8; ++i) {
      int r = tid * 8 + i;
      acc += (labels[r] <= 3) ? sc[r][0] : sc[r][1];
    }
    acc *= (1.f / 8.f);
    out[tid] = 1.f / (1.f + __expf(-acc));
  }
}

// ---------------------------------------------------------------------------
extern "C" void kernel_launch(void* const* d_in, const int* in_sizes, int n_in,
                              void* d_out, int out_size, void* d_ws, size_t ws_size,
                              hipStream_t stream) {
  const float* vid  = (const float*)d_in[0];
  const float* txt  = (const float*)d_in[1];
  const int* labels = (const int*)d_in[2];
  const float* vWxf = (const float*)d_in[3];
  const float* vWhf = (const float*)d_in[4];
  const float* vbf  = (const float*)d_in[5];
  const float* vWxb = (const float*)d_in[6];
  const float* vWhb = (const float*)d_in[7];
  const float* vbb  = (const float*)d_in[8];
  const float* tWxf = (const float*)d_in[9];
  const float* tWhf = (const float*)d_in[10];
  const float* tbf  = (const float*)d_in[11];
  const float* tWxb = (const float*)d_in[12];
  const float* tWhb = (const float*)d_in[13];
  const float* tbb  = (const float*)d_in[14];
  const float* sqW1 = (const float*)d_in[15];
  const float* sqb1 = (const float*)d_in[16];
  const float* sqW2 = (const float*)d_in[17];
  const float* sqb2 = (const float*)d_in[18];
  const float* rqW1 = (const float*)d_in[19];
  const float* rqb1 = (const float*)d_in[20];
  const float* rqW2 = (const float*)d_in[21];
  const float* rqb2 = (const float*)d_in[22];

  char* p = (char*)d_ws;
  auto alloc = [&](size_t bytes) {
    char* r = p;
    p += (bytes + 255) & ~(size_t)255;
    return r;
  };
  bf16_t* vWxf_sw = (bf16_t*)alloc((size_t)1024 * 2048 * 2);
  bf16_t* vWxb_sw = (bf16_t*)alloc((size_t)1024 * 2048 * 2);
  bf16_t* vWh_sw  = (bf16_t*)alloc((size_t)2 * 512 * 2048 * 2);  // [dir]
  bf16_t* tWxf_sw = (bf16_t*)alloc((size_t)512 * 2048 * 2);
  bf16_t* tWxb_sw = (bf16_t*)alloc((size_t)512 * 2048 * 2);
  bf16_t* tWh_sw  = (bf16_t*)alloc((size_t)2 * 512 * 2048 * 2);  // [dir]
  bf16_t* W1_sw   = (bf16_t*)alloc((size_t)2 * 2048 * 512 * 2);  // [mlp]
  bf16_t* xg_vid  = (bf16_t*)alloc((size_t)2 * 256 * 128 * 2048 * 2);
  bf16_t* xg_txt  = (bf16_t*)alloc((size_t)2 * 64 * 128 * 2048 * 2);
  bf16_t* h_vid   = (bf16_t*)alloc((size_t)2 * 2 * 128 * 512 * 2);
  bf16_t* h_txt   = (bf16_t*)alloc((size_t)2 * 2 * 128 * 512 * 2);
  float*  c_vid   = (float*)alloc((size_t)2 * 128 * 512 * 4);
  float*  c_txt   = (float*)alloc((size_t)2 * 128 * 512 * 4);
  bf16_t* feats   = (bf16_t*)alloc((size_t)128 * 2048 * 2);
  float*  h1      = (float*)alloc((size_t)2 * 128 * 512 * 4);
  (void)ws_size; (void)in_sizes; (void)n_in; (void)out_size;

  auto prep = [&](const float* s, bf16_t* d, int K, int N) {
    int total = (K / 32) * (N / 16) * 64;
    k_prep<<<(total + 255) / 256, 256, 0, stream>>>(s, d, K, N);
  };
  prep(vWxf, vWxf_sw, 1024, 2048);
  prep(vWxb, vWxb_sw, 1024, 2048);
  prep(vWhf, vWh_sw, 512, 2048);
  prep(vWhb, vWh_sw + (size_t)512 * 2048, 512, 2048);
  prep(tWxf, tWxf_sw, 512, 2048);
  prep(tWxb, tWxb_sw, 512, 2048);
  prep(tWhf, tWh_sw, 512, 2048);
  prep(tWhb, tWh_sw + (size_t)512 * 2048, 512, 2048);
  prep(sqW1, W1_sw, 2048, 512);
  prep(rqW1, W1_sw + (size_t)2048 * 512, 2048, 512);

  // zero h parity buffers + c state (h_vid..c_txt are contiguous: 2 MB)
  hipMemsetAsync(h_vid, 0, (size_t)4 * 524288, stream);

  size_t xgv_dir = (size_t)256 * 128 * 2048;
  size_t xgt_dir = (size_t)64 * 128 * 2048;
  k_proj<1024><<<256 * 8, 256, 0, stream>>>(vid, 256, 0, vWxf_sw, vbf, xg_vid);
  k_proj<1024><<<256 * 8, 256, 0, stream>>>(vid, 256, 1, vWxb_sw, vbb, xg_vid + xgv_dir);
  k_proj<512><<<64 * 8, 256, 0, stream>>>(txt, 64, 0, tWxf_sw, tbf, xg_txt);
  k_proj<512><<<64 * 8, 256, 0, stream>>>(txt, 64, 1, tWxb_sw, tbb, xg_txt + xgt_dir);

  for (int s = 0; s < 256; ++s) {
    int nwg = (s < 64) ? 256 : 128;
    k_step<<<nwg, 256, 0, stream>>>(xg_vid, xg_txt, vWh_sw, tWh_sw, h_vid, h_txt,
                                    c_vid, c_txt, feats, s);
  }

  k_mlp<<<16, 256, 0, stream>>>(feats, W1_sw, sqb1, rqb1, h1);
  k_final<<<1, 256, 0, stream>>>(h1, sqW2, sqb2, rqW2, rqb2, labels, (float*)d_out);
}